// Round 6
// baseline (139.484 us; speedup 1.0000x reference)
//
#include <hip/hip_runtime.h>
#include <hip/hip_bf16.h>

typedef __hip_bfloat16 bf16;
typedef short bf16x8 __attribute__((ext_vector_type(8)));
typedef float f32x4 __attribute__((ext_vector_type(4)));

#define S_LEN 4096
#define NBATCH 2
#define EDIM 1024
#define DDIM 64
#define MROWS (NBATCH * S_LEN)   // 8192

#define GLOBAL_AS __attribute__((address_space(1)))
#define LDS_AS __attribute__((address_space(3)))

union frag_u { bf16x8 v; bf16 e[8]; };

// async 16B global -> LDS (dest = wave-uniform base + lane*16)
__device__ __forceinline__ void async_ld16(const float* gp, float* lp) {
  __builtin_amdgcn_global_load_lds((const GLOBAL_AS void*)gp,
                                   (LDS_AS void*)lp, 16, 0, 0);
}

// f32x8 -> split bf16 hi/lo fragments (x ~= hi + lo, rel err ~2^-17)
__device__ __forceinline__ void cvt_split(const float4& a, const float4& b,
                                          bf16x8& hi, bf16x8& lo) {
  float v[8] = {a.x, a.y, a.z, a.w, b.x, b.y, b.z, b.w};
  frag_u h, l;
#pragma unroll
  for (int e = 0; e < 8; e++) {
    bf16 hh = __float2bfloat16(v[e]);
    h.e[e] = hh;
    l.e[e] = __float2bfloat16(v[e] - __bfloat162float(hh));
  }
  hi = h.v;
  lo = l.v;
}

// ---------------------------------------------------------------------------
// Pack weights (f32, k-major [1024][64]) -> split bf16 hi/lo, layout
// Wt[192 n-rows][1024 k] so MFMA B-fragments are 16B contiguous loads.
// LDS 64x65 transpose: coalesced reads AND coalesced writes (old version's
// stride-256B scatter reads were latency-bound).
// Grid 48 = 3 mats x 16 k-blocks. Block 0 also zeroes Vsum.
// ---------------------------------------------------------------------------
__global__ __launch_bounds__(256) void pack_w_kernel(
    const float* __restrict__ Wq, const float* __restrict__ Wk,
    const float* __restrict__ Wv, bf16* __restrict__ Wt_hi,
    bf16* __restrict__ Wt_lo, float* __restrict__ Vsum) {
  __shared__ float tile[64 * 65];
  const int mat = blockIdx.x >> 4;
  const int kb = (blockIdx.x & 15) * 64;
  const int t = threadIdx.x;
  if (blockIdx.x == 0 && t < NBATCH * DDIM) Vsum[t] = 0.f;
  const float* W = (mat == 0) ? Wq : ((mat == 1) ? Wk : Wv);

  // load 64k x 64n tile (coalesced float4), store transposed [n][k] padded
#pragma unroll
  for (int i = 0; i < 4; i++) {
    int F = (i * 256 + t) * 4;          // flat f32 index in [0,4096)
    int k = F >> 6;
    int n4 = F & 63;
    float4 v = *(const float4*)(const void*)(W + (size_t)(kb + k) * 64 + n4);
    tile[(n4 + 0) * 65 + k] = v.x;
    tile[(n4 + 1) * 65 + k] = v.y;
    tile[(n4 + 2) * 65 + k] = v.z;
    tile[(n4 + 3) * 65 + k] = v.w;
  }
  __syncthreads();

  // write out: thread t -> n = t/4, k-chunk 16 (coalesced 16B stores)
  const int n = t >> 2;
  const int kc = (t & 3) * 16;
  frag_u h0, h1, l0, l1;
#pragma unroll
  for (int e = 0; e < 8; e++) {
    float v0 = tile[n * 65 + kc + e];
    float v1 = tile[n * 65 + kc + 8 + e];
    bf16 a = __float2bfloat16(v0);
    bf16 b = __float2bfloat16(v1);
    h0.e[e] = a;
    h1.e[e] = b;
    l0.e[e] = __float2bfloat16(v0 - __bfloat162float(a));
    l1.e[e] = __float2bfloat16(v1 - __bfloat162float(b));
  }
  size_t obase = (size_t)(mat * 64 + n) * EDIM + kb + kc;
  *(bf16x8*)(void*)(Wt_hi + obase) = h0.v;
  *(bf16x8*)(void*)(Wt_hi + obase + 8) = h1.v;
  *(bf16x8*)(void*)(Wt_lo + obase) = l0.v;
  *(bf16x8*)(void*)(Wt_lo + obase + 8) = l1.v;
}

// ---------------------------------------------------------------------------
// Fused QKV GEMM, m97-style async-LDS staging. M=8192, K=1024, N=192.
// Grid 256 x 512 threads (8 waves/block, 1 block/CU).
// Wave (p,mh,nw): p = kphase (k half), mh = 16-row half, nw = 96-col half.
// Per staging round j (8 rounds): x-tile [32 rows][128 cols] f32 staged via
// global_load_lds; cols 0..63 = k in [j*64, +64), cols 64..127 = same + 512.
// XOR swizzle on 8-f32 groups (g' = g ^ (row&7)) keeps staging lane-
// contiguous while making frag ds_read_b128s only 4-way bank-conflicted.
// B-frags (pre-packed split-bf16 Wt, 768 KB, L2-resident) loaded direct.
// Epilogue: kphase1 -> LDS, kphase0 adds + bias + store. No atomics.
// mfma_f32_16x16x32_bf16 split (xh*wh + xh*wl + xl*wh):
//   A-frag: A[m][k], m = lane&15, k = (lane>>4)*8 + j
//   B-frag: B[k][n], n = lane&15, k = (lane>>4)*8 + j
//   D:      D[m][n], m = (lane>>4)*4 + reg, n = lane&15
// ---------------------------------------------------------------------------
__global__ __launch_bounds__(512, 2) void qkv_gemm_kernel(
    const float* __restrict__ x, const bf16* __restrict__ Wt_hi,
    const bf16* __restrict__ Wt_lo, const float* __restrict__ bq,
    const float* __restrict__ bk, const float* __restrict__ bv,
    float* __restrict__ qkv) {
  __shared__ float lds[6144];   // staging uses [0,4096); epilogue uses all 24KB
  const int tid = threadIdx.x;
  const int lane = tid & 63;
  const int wave = tid >> 6;
  const int quad = lane >> 4;
  const int l16 = lane & 15;
  const int p = wave >> 2;            // kphase: k in [p*512, p*512+512)
  const int mh = (wave >> 1) & 1;     // row half (16 rows)
  const int nw = wave & 1;            // col half (6 n-tiles)
  const int rowBase = blockIdx.x * 32;
  const int rA = mh * 16 + l16;

  // staging source decode for this thread's two 16B slots
  int s0 = wave * 256 + lane * 4;                  // physical f32 slot
  int s1 = 2048 + wave * 256 + lane * 4;
  int r0 = s0 >> 7, pc0 = s0 & 127;
  int r1 = s1 >> 7, pc1 = s1 & 127;
  int c0 = ((((pc0 >> 3) ^ (r0 & 7)) << 3) | (pc0 & 7));   // logical col
  int c1 = ((((pc1 >> 3) ^ (r1 & 7)) << 3) | (pc1 & 7));
  const float* gsrc0 = x + (size_t)(rowBase + r0) * EDIM + (c0 >> 6) * 512 + (c0 & 63);
  const float* gsrc1 = x + (size_t)(rowBase + r1) * EDIM + (c1 >> 6) * 512 + (c1 & 63);
  float* ldst0 = &lds[wave * 256];                 // wave-uniform dests
  float* ldst1 = &lds[2048 + wave * 256];

  // B row offsets for this wave's 6 n-tiles (k part added per step)
  int bidx[6];
#pragma unroll
  for (int t = 0; t < 6; t++)
    bidx[t] = ((nw * 6 + t) * 16 + l16) * EDIM + quad * 8 + p * 512;

  f32x4 acc[6];
#pragma unroll
  for (int t = 0; t < 6; t++) acc[t] = (f32x4){0.f, 0.f, 0.f, 0.f};

  for (int j = 0; j < 8; j++) {
    if (j) __syncthreads();                        // prev compute done
    async_ld16(gsrc0 + j * 64, ldst0);
    async_ld16(gsrc1 + j * 64, ldst1);
    __syncthreads();                               // staging visible

#pragma unroll
    for (int u = 0; u < 2; u++) {
      int cc = p * 64 + u * 32 + quad * 8;         // logical col of A-frag
      int gsw = ((cc >> 3) ^ (rA & 7));            // swizzled group
      const float* aptr = &lds[rA * 128 + gsw * 8];
      float4 a0 = *(const float4*)(const void*)aptr;
      float4 a1 = *(const float4*)(const void*)(aptr + 4);
      bf16x8 ah, al;
      cvt_split(a0, a1, ah, al);
      int koff = j * 64 + u * 32;
#pragma unroll
      for (int t = 0; t < 6; t++) {
        bf16x8 bh = *(const bf16x8*)(const void*)(Wt_hi + bidx[t] + koff);
        bf16x8 bl = *(const bf16x8*)(const void*)(Wt_lo + bidx[t] + koff);
        acc[t] = __builtin_amdgcn_mfma_f32_16x16x32_bf16(ah, bh, acc[t], 0, 0, 0);
        acc[t] = __builtin_amdgcn_mfma_f32_16x16x32_bf16(ah, bl, acc[t], 0, 0, 0);
        acc[t] = __builtin_amdgcn_mfma_f32_16x16x32_bf16(al, bh, acc[t], 0, 0, 0);
      }
    }
  }

  // cross-kphase reduction through LDS (aliases staging area -> barrier first)
  __syncthreads();
  if (p == 1) {
#pragma unroll
    for (int t = 0; t < 6; t++) {
      int n = (nw * 6 + t) * 16 + l16;
#pragma unroll
      for (int r = 0; r < 4; r++) {
        int row = mh * 16 + quad * 4 + r;
        lds[row * 192 + n] = acc[t][r];
      }
    }
  }
  __syncthreads();
  if (p == 0) {
#pragma unroll
    for (int t = 0; t < 6; t++) {
      int n = (nw * 6 + t) * 16 + l16;
      int mat = n >> 6;
      int col = n & 63;
      float bias = (mat == 0) ? bq[col] : ((mat == 1) ? bk[col] : bv[col]);
      float* dst = qkv + (size_t)mat * MROWS * DDIM +
                   (size_t)(rowBase + mh * 16 + quad * 4) * DDIM + col;
#pragma unroll
      for (int r = 0; r < 4; r++) {
        int row = mh * 16 + quad * 4 + r;
        dst[r * DDIM] = acc[t][r] + lds[row * 192 + n] + bias;
      }
    }
  }
}

// ---------------------------------------------------------------------------
// Per-batch column sums of V (for the exp(0) background term).
// ---------------------------------------------------------------------------
__global__ __launch_bounds__(256) void vsum_kernel(const float* __restrict__ Vf,
                                                   float* __restrict__ Vsum) {
  int b = blockIdx.x >> 5;
  int chunk = blockIdx.x & 31;
  int col = threadIdx.x & 63;
  int rg = threadIdx.x >> 6;
  const float* base =
      Vf + ((size_t)b * S_LEN + chunk * 128 + rg * 32) * DDIM + col;
  float s = 0.f;
#pragma unroll
  for (int r = 0; r < 32; r++) s += base[r * DDIM];
  __shared__ float red[256];
  red[threadIdx.x] = s;
  __syncthreads();
  if (threadIdx.x < 64)
    atomicAdd(&Vsum[b * DDIM + col],
              red[col] + red[col + 64] + red[col + 128] + red[col + 192]);
}

// ---------------------------------------------------------------------------
// Attention: 2 queries per wave, 32 lanes each, lane owns a float2 dim-pair.
// Full-row softmax collapses to: 5 window exps + (S - nvalid) background
// exp(0-m) terms; background numerator = Vsum - sum(window V).
// ---------------------------------------------------------------------------
__global__ __launch_bounds__(256) void attn_kernel(
    const float* __restrict__ Qf, const float* __restrict__ Kf,
    const float* __restrict__ Vf, const float* __restrict__ Vsum,
    float* __restrict__ out) {
  int l = threadIdx.x & 31;
  int qidx = blockIdx.x * 8 + (threadIdx.x >> 5);
  int b = qidx >> 12;
  int i = qidx & 4095;

  float2 q = *(const float2*)(const void*)(Qf + (size_t)qidx * DDIM + 2 * l);
  float sc[5];
  float2 vv[5];
  bool val[5];
#pragma unroll
  for (int w = 0; w < 5; w++) {
    int j = i + 2 * w - 4;
    val[w] = (j >= 0) && (j < S_LEN);
    int jj = val[w] ? j : i;
    size_t off = (size_t)(b * S_LEN + jj) * DDIM + 2 * l;
    float2 kk = *(const float2*)(const void*)(Kf + off);
    vv[w] = *(const float2*)(const void*)(Vf + off);
    float p = q.x * kk.x + q.y * kk.y;
#pragma unroll
    for (int d = 1; d < 32; d <<= 1) p += __shfl_xor(p, d, 64);
    sc[w] = p;
  }

  float mx = 0.f;
#pragma unroll
  for (int w = 0; w < 5; w++)
    if (val[w]) mx = fmaxf(mx, sc[w]);

  float denom = 0.f;
  float2 accv = {0.f, 0.f}, vsel = {0.f, 0.f};
  int nval = 0;
#pragma unroll
  for (int w = 0; w < 5; w++)
    if (val[w]) {
      float pexp = __expf(sc[w] - mx);
      denom += pexp;
      accv.x += pexp * vv[w].x;
      accv.y += pexp * vv[w].y;
      vsel.x += vv[w].x;
      vsel.y += vv[w].y;
      nval++;
    }
  float p0 = __expf(-mx);
  denom += p0 * (float)(S_LEN - nval);
  float2 vs = *(const float2*)(const void*)(Vsum + b * DDIM + 2 * l);
  accv.x += p0 * (vs.x - vsel.x);
  accv.y += p0 * (vs.y - vsel.y);

  float2 o = {accv.x / denom, accv.y / denom};
  *(float2*)(void*)(out + (size_t)qidx * DDIM + 2 * l) = o;
}

// ---------------------------------------------------------------------------
extern "C" void kernel_launch(void* const* d_in, const int* in_sizes, int n_in,
                              void* d_out, int out_size, void* d_ws,
                              size_t ws_size, hipStream_t stream) {
  const float* x = (const float*)d_in[0];
  const float* Wq = (const float*)d_in[1];
  const float* bq = (const float*)d_in[2];
  const float* Wk = (const float*)d_in[3];
  const float* bk = (const float*)d_in[4];
  const float* Wv = (const float*)d_in[5];
  const float* bv = (const float*)d_in[6];
  float* out = (float*)d_out;

  char* ws = (char*)d_ws;
  bf16* Wt_hi = (bf16*)ws;                    // 393216 B
  bf16* Wt_lo = (bf16*)(ws + 393216);         // 393216 B
  float* qkv = (float*)(ws + 786432);         // 6291456 B
  float* Qf = qkv;
  float* Kf = qkv + (size_t)MROWS * DDIM;
  float* Vf = Kf + (size_t)MROWS * DDIM;
  float* Vsum = (float*)(ws + 786432 + 6291456);  // 128 floats
  // total workspace: ~7.08 MB

  hipLaunchKernelGGL(pack_w_kernel, dim3(48), dim3(256), 0, stream, Wq, Wk, Wv,
                     Wt_hi, Wt_lo, Vsum);
  hipLaunchKernelGGL(qkv_gemm_kernel, dim3(256), dim3(512), 0, stream, x, Wt_hi,
                     Wt_lo, bq, bk, bv, qkv);
  hipLaunchKernelGGL(vsum_kernel, dim3(64), dim3(256), 0, stream, Vf, Vsum);
  hipLaunchKernelGGL(attn_kernel, dim3(1024), dim3(256), 0, stream, Qf, Kf, Vf,
                     Vsum, out);
}

// Round 7
// 122.367 us; speedup vs baseline: 1.1399x; 1.1399x over previous
//
#include <hip/hip_runtime.h>
#include <hip/hip_bf16.h>

typedef __hip_bfloat16 bf16;
typedef short bf16x8 __attribute__((ext_vector_type(8)));
typedef float f32x4 __attribute__((ext_vector_type(4)));

#define S_LEN 4096
#define NBATCH 2
#define EDIM 1024
#define DDIM 64
#define MROWS (NBATCH * S_LEN)   // 8192

#define GLOBAL_AS __attribute__((address_space(1)))
#define LDS_AS __attribute__((address_space(3)))

union frag_u { bf16x8 v; bf16 e[8]; };

// async 16B global -> LDS (LDS dest must be wave-uniform; HW adds lane*16)
__device__ __forceinline__ void async_ld16_f(const float* gp, float* lp) {
  __builtin_amdgcn_global_load_lds((const GLOBAL_AS void*)gp,
                                   (LDS_AS void*)lp, 16, 0, 0);
}
__device__ __forceinline__ void async_ld16_b(const bf16* gp, bf16* lp) {
  __builtin_amdgcn_global_load_lds((const GLOBAL_AS void*)gp,
                                   (LDS_AS void*)lp, 16, 0, 0);
}

// f32x8 -> split bf16 hi/lo fragments (x ~= hi + lo, rel err ~2^-17)
__device__ __forceinline__ void cvt_split(const float4& a, const float4& b,
                                          bf16x8& hi, bf16x8& lo) {
  float v[8] = {a.x, a.y, a.z, a.w, b.x, b.y, b.z, b.w};
  frag_u h, l;
#pragma unroll
  for (int e = 0; e < 8; e++) {
    bf16 hh = __float2bfloat16(v[e]);
    h.e[e] = hh;
    l.e[e] = __float2bfloat16(v[e] - __bfloat162float(hh));
  }
  hi = h.v;
  lo = l.v;
}

// ---------------------------------------------------------------------------
// Pack weights (f32, k-major [1024][64]) -> split bf16 hi/lo, layout
// Wt[192 n-rows][1024 k]. LDS 64x65 transpose keeps both directions
// coalesced. Grid 48 = 3 mats x 16 k-blocks. Block 0 zeroes Vsum.
// ---------------------------------------------------------------------------
__global__ __launch_bounds__(256) void pack_w_kernel(
    const float* __restrict__ Wq, const float* __restrict__ Wk,
    const float* __restrict__ Wv, bf16* __restrict__ Wt_hi,
    bf16* __restrict__ Wt_lo, float* __restrict__ Vsum) {
  __shared__ float tile[64 * 65];
  const int mat = blockIdx.x >> 4;
  const int kb = (blockIdx.x & 15) * 64;
  const int t = threadIdx.x;
  if (blockIdx.x == 0 && t < NBATCH * DDIM) Vsum[t] = 0.f;
  const float* W = (mat == 0) ? Wq : ((mat == 1) ? Wk : Wv);

#pragma unroll
  for (int i = 0; i < 4; i++) {
    int F = (i * 256 + t) * 4;          // flat f32 index in [0,4096)
    int k = F >> 6;
    int n4 = F & 63;
    float4 v = *(const float4*)(const void*)(W + (size_t)(kb + k) * 64 + n4);
    tile[(n4 + 0) * 65 + k] = v.x;
    tile[(n4 + 1) * 65 + k] = v.y;
    tile[(n4 + 2) * 65 + k] = v.z;
    tile[(n4 + 3) * 65 + k] = v.w;
  }
  __syncthreads();

  const int n = t >> 2;
  const int kc = (t & 3) * 16;
  frag_u h0, h1, l0, l1;
#pragma unroll
  for (int e = 0; e < 8; e++) {
    float v0 = tile[n * 65 + kc + e];
    float v1 = tile[n * 65 + kc + 8 + e];
    bf16 a = __float2bfloat16(v0);
    bf16 b = __float2bfloat16(v1);
    h0.e[e] = a;
    h1.e[e] = b;
    l0.e[e] = __float2bfloat16(v0 - __bfloat162float(a));
    l1.e[e] = __float2bfloat16(v1 - __bfloat162float(b));
  }
  size_t obase = (size_t)(mat * 64 + n) * EDIM + kb + kc;
  *(bf16x8*)(void*)(Wt_hi + obase) = h0.v;
  *(bf16x8*)(void*)(Wt_hi + obase + 8) = h1.v;
  *(bf16x8*)(void*)(Wt_lo + obase) = l0.v;
  *(bf16x8*)(void*)(Wt_lo + obase + 8) = l1.v;
}

// ---------------------------------------------------------------------------
// Fused QKV GEMM v3: ALL traffic through async LDS staging (the round 4-6
// disease was B-frags as direct global loads -> serialized L2 latency).
// M=8192, K=1024, N=192. Grid 256 = 128 m-blocks x 2 k-halves; 512 threads.
// Per round j (16 rounds of BK=32): stage A-tile [4g][64row][8] f32 (8KB)
// and B-tiles [4g][192n][8] split-bf16 (12KB hi + 12KB lo) via
// global_load_lds, then frags are contiguous ds_read_b128.
// Wave (mh, nq): mh = 32-row half, nq = 3 n-tiles; per round per wave:
// 10 ds_read_b128 + 18 MFMA (split-bf16: xh*wh + xh*wl + xl*wh).
// K-halves write part0 (with bias) / part1 (no bias); attn adds them.
// Epilogue also shuffle-reduces V columns -> atomicAdd into Vsum
// (replaces the old vsum kernel; Vsum = sum_s V[s] incl. bias).
//   A-frag: A[m][k], m = lane&15, k = (lane>>4)*8 + j
//   B-frag: B[k][n], n = lane&15, k = (lane>>4)*8 + j
//   D:      D[m][n], m = (lane>>4)*4 + reg, n = lane&15
// ---------------------------------------------------------------------------
__global__ __launch_bounds__(512, 2) void qkv_gemm_kernel(
    const float* __restrict__ x, const bf16* __restrict__ Wt_hi,
    const bf16* __restrict__ Wt_lo, const float* __restrict__ bq,
    const float* __restrict__ bk, const float* __restrict__ bv,
    float* __restrict__ part0, float* __restrict__ part1,
    float* __restrict__ Vsum) {
  __shared__ float As[4 * 64 * 8];    // 8KB   [g][row][e]
  __shared__ bf16 Bh[4 * 192 * 8];    // 12KB  [g][n][e]
  __shared__ bf16 Bl[4 * 192 * 8];    // 12KB
  const int tid = threadIdx.x;
  const int lane = tid & 63;
  const int wave = tid >> 6;
  const int quad = lane >> 4;
  const int l16 = lane & 15;
  const int mb = blockIdx.x >> 1;
  const int p = blockIdx.x & 1;       // k-half
  const int rowBase = mb * 64;
  const int kbase = p * 512;
  const int mh = wave >> 2;           // 32-row half
  const int nq = wave & 3;            // n-tile triple

  // --- staging decode (A: 1 chunk/wave; B hi/lo: chunk wave, + wave+8 for
  // waves 0-3; each chunk = 64 lanes x 16B, LDS dest wave-uniform) ---
  int aslot = wave * 64 + lane;               // 512 slots (8KB/16B)
  int af = aslot * 4;
  const float* asrc = x + (size_t)(rowBase + ((af >> 3) & 63)) * EDIM + kbase +
                      (af >> 9) * 8 + (af & 7);
  float* adst = As + wave * 256;

  int bslot0 = wave * 64 + lane;              // 768 slots (12KB/16B)
  int bg0 = bslot0 / 192, bn0 = bslot0 - bg0 * 192;
  const bf16* bhsrc0 = Wt_hi + (size_t)bn0 * EDIM + kbase + bg0 * 8;
  const bf16* blsrc0 = Wt_lo + (size_t)bn0 * EDIM + kbase + bg0 * 8;
  bf16* bhdst0 = Bh + wave * 512;
  bf16* bldst0 = Bl + wave * 512;

  int bslot1 = (wave + 8) * 64 + lane;        // only waves 0-3 use this
  int bg1 = bslot1 / 192, bn1 = bslot1 - bg1 * 192;
  const bf16* bhsrc1 = Wt_hi + (size_t)bn1 * EDIM + kbase + bg1 * 8;
  const bf16* blsrc1 = Wt_lo + (size_t)bn1 * EDIM + kbase + bg1 * 8;
  bf16* bhdst1 = Bh + (wave + 8) * 512;
  bf16* bldst1 = Bl + (wave + 8) * 512;

  f32x4 acc[2][3];
#pragma unroll
  for (int mt = 0; mt < 2; mt++)
#pragma unroll
    for (int t = 0; t < 3; t++) acc[mt][t] = (f32x4){0.f, 0.f, 0.f, 0.f};

  for (int j = 0; j < 16; j++) {
    if (j) __syncthreads();                   // prev round's frags consumed
    async_ld16_f(asrc + j * 32, adst);
    async_ld16_b(bhsrc0 + j * 32, bhdst0);
    async_ld16_b(blsrc0 + j * 32, bldst0);
    if (wave < 4) {
      async_ld16_b(bhsrc1 + j * 32, bhdst1);
      async_ld16_b(blsrc1 + j * 32, bldst1);
    }
    __syncthreads();                          // staging visible (vmcnt drain)

    bf16x8 ah[2], al[2];
#pragma unroll
    for (int mt = 0; mt < 2; mt++) {
      const float* ap = As + quad * 512 + (mh * 32 + mt * 16 + l16) * 8;
      float4 a0 = *(const float4*)(const void*)ap;
      float4 a1 = *(const float4*)(const void*)(ap + 4);
      cvt_split(a0, a1, ah[mt], al[mt]);
    }
#pragma unroll
    for (int t = 0; t < 3; t++) {
      int n = (nq * 3 + t) * 16 + l16;
      bf16x8 bh = *(const bf16x8*)(const void*)(Bh + quad * 1536 + n * 8);
      bf16x8 bl = *(const bf16x8*)(const void*)(Bl + quad * 1536 + n * 8);
#pragma unroll
      for (int mt = 0; mt < 2; mt++) {
        acc[mt][t] = __builtin_amdgcn_mfma_f32_16x16x32_bf16(ah[mt], bh, acc[mt][t], 0, 0, 0);
        acc[mt][t] = __builtin_amdgcn_mfma_f32_16x16x32_bf16(ah[mt], bl, acc[mt][t], 0, 0, 0);
        acc[mt][t] = __builtin_amdgcn_mfma_f32_16x16x32_bf16(al[mt], bh, acc[mt][t], 0, 0, 0);
      }
    }
  }

  // --- epilogue: biased store to this k-half's partial buffer + V col-sums ---
  const int b = rowBase >> 12;
  float* partp = p ? part1 : part0;
#pragma unroll
  for (int t = 0; t < 3; t++) {
    int nidx = nq * 3 + t;                    // n-tile index 0..11
    int n = nidx * 16 + l16;
    int mat = n >> 6;
    int col = n & 63;
    float bias = (p == 0)
                     ? ((mat == 0) ? bq[col] : ((mat == 1) ? bk[col] : bv[col]))
                     : 0.f;
    float vsum_part = 0.f;
#pragma unroll
    for (int mt = 0; mt < 2; mt++) {
      float* dst = partp + (size_t)mat * MROWS * DDIM +
                   (size_t)(rowBase + mh * 32 + mt * 16 + quad * 4) * DDIM + col;
#pragma unroll
      for (int r = 0; r < 4; r++) {
        float val = acc[mt][t][r] + bias;
        dst[r * DDIM] = val;
        vsum_part += val;
      }
    }
    if (nidx >= 8) {                          // V tiles: reduce cols into Vsum
      vsum_part += __shfl_xor(vsum_part, 16, 64);
      vsum_part += __shfl_xor(vsum_part, 32, 64);
      if (quad == 0) atomicAdd(&Vsum[b * DDIM + (n - 128)], vsum_part);
    }
  }
}

// ---------------------------------------------------------------------------
// Attention: 2 queries per wave, 32 lanes each, lane owns a float2 dim-pair.
// Q/K/V assembled as part0 + part1 (k-split partials; bias in part0).
// Full-row softmax collapses to: 5 window exps + (S - nvalid) background
// exp(0-m) terms; background numerator = Vsum - sum(window V).
// ---------------------------------------------------------------------------
__global__ __launch_bounds__(256) void attn_kernel(
    const float* __restrict__ p0, const float* __restrict__ p1,
    const float* __restrict__ Vsum, float* __restrict__ out) {
  const float* Q0 = p0;
  const float* K0 = p0 + (size_t)MROWS * DDIM;
  const float* V0 = p0 + (size_t)2 * MROWS * DDIM;
  const float* Q1 = p1;
  const float* K1 = p1 + (size_t)MROWS * DDIM;
  const float* V1 = p1 + (size_t)2 * MROWS * DDIM;

  int l = threadIdx.x & 31;
  int qidx = blockIdx.x * 8 + (threadIdx.x >> 5);
  int b = qidx >> 12;
  int i = qidx & 4095;

  size_t qoff = (size_t)qidx * DDIM + 2 * l;
  float2 qa = *(const float2*)(const void*)(Q0 + qoff);
  float2 qb = *(const float2*)(const void*)(Q1 + qoff);
  float2 q = {qa.x + qb.x, qa.y + qb.y};

  float sc[5];
  float2 vv[5];
  bool val[5];
#pragma unroll
  for (int w = 0; w < 5; w++) {
    int j = i + 2 * w - 4;
    val[w] = (j >= 0) && (j < S_LEN);
    int jj = val[w] ? j : i;
    size_t off = (size_t)(b * S_LEN + jj) * DDIM + 2 * l;
    float2 k0 = *(const float2*)(const void*)(K0 + off);
    float2 k1 = *(const float2*)(const void*)(K1 + off);
    float2 v0 = *(const float2*)(const void*)(V0 + off);
    float2 v1 = *(const float2*)(const void*)(V1 + off);
    vv[w] = (float2){v0.x + v1.x, v0.y + v1.y};
    float p = q.x * (k0.x + k1.x) + q.y * (k0.y + k1.y);
#pragma unroll
    for (int d = 1; d < 32; d <<= 1) p += __shfl_xor(p, d, 64);
    sc[w] = p;
  }

  float mx = 0.f;  // include the background score 0 in the max
#pragma unroll
  for (int w = 0; w < 5; w++)
    if (val[w]) mx = fmaxf(mx, sc[w]);

  float denom = 0.f;
  float2 accv = {0.f, 0.f}, vsel = {0.f, 0.f};
  int nval = 0;
#pragma unroll
  for (int w = 0; w < 5; w++)
    if (val[w]) {
      float pexp = __expf(sc[w] - mx);
      denom += pexp;
      accv.x += pexp * vv[w].x;
      accv.y += pexp * vv[w].y;
      vsel.x += vv[w].x;
      vsel.y += vv[w].y;
      nval++;
    }
  float pbg = __expf(-mx);
  denom += pbg * (float)(S_LEN - nval);
  float2 vs = *(const float2*)(const void*)(Vsum + b * DDIM + 2 * l);
  accv.x += pbg * (vs.x - vsel.x);
  accv.y += pbg * (vs.y - vsel.y);

  float2 o = {accv.x / denom, accv.y / denom};
  *(float2*)(void*)(out + (size_t)qidx * DDIM + 2 * l) = o;
}

// ---------------------------------------------------------------------------
extern "C" void kernel_launch(void* const* d_in, const int* in_sizes, int n_in,
                              void* d_out, int out_size, void* d_ws,
                              size_t ws_size, hipStream_t stream) {
  const float* x = (const float*)d_in[0];
  const float* Wq = (const float*)d_in[1];
  const float* bq = (const float*)d_in[2];
  const float* Wk = (const float*)d_in[3];
  const float* bk = (const float*)d_in[4];
  const float* Wv = (const float*)d_in[5];
  const float* bv = (const float*)d_in[6];
  float* out = (float*)d_out;

  char* ws = (char*)d_ws;
  bf16* Wt_hi = (bf16*)ws;                            // 393216 B
  bf16* Wt_lo = (bf16*)(ws + 393216);                 // 393216 B
  float* part0 = (float*)(ws + 786432);               // 6291456 B
  float* part1 = (float*)(ws + 786432 + 6291456);     // 6291456 B
  float* Vsum = (float*)(ws + 786432 + 2 * 6291456);  // 512 B
  // total workspace: ~12.75 MB

  hipLaunchKernelGGL(pack_w_kernel, dim3(48), dim3(256), 0, stream, Wq, Wk, Wv,
                     Wt_hi, Wt_lo, Vsum);
  hipLaunchKernelGGL(qkv_gemm_kernel, dim3(256), dim3(512), 0, stream, x, Wt_hi,
                     Wt_lo, bq, bk, bv, part0, part1, Vsum);
  hipLaunchKernelGGL(attn_kernel, dim3(1024), dim3(256), 0, stream, part0,
                     part1, Vsum, out);
}